// Round 1
// baseline (5899.784 us; speedup 1.0000x reference)
//
#include <hip/hip_runtime.h>

// ---------------------------------------------------------------------------
// Encoder_conv: emb (1x1 conv) -> 3x { multi-tap K=2 convs summed -> LSTM scan
// with per-step attention gating }.
// B=32, W=512, H=256, 4H=1024, NINP=128, K=2, NLAYERS=3.
//
// Design (round 1, correctness-first):
//  - all matmul-ish work in f16 storage with v_dot2_f32_f16 (fp32 accum)
//  - conv-as-GEMM, LDS-tiled, 64x64 tiles, one kernel per layer summing nl taps
//  - recurrence: 1 WG per batch (32 WGs x 1024 thr), rw row split:
//      d 0..103  -> VGPRs (packed f16 pairs)
//      d 104..118 -> LDS (stride 15 -> conflict-free)
//      d 119..127 -> global (L2-resident, reloaded per step)
//    hx broadcast via LDS (f16), gates exchanged via LDS f16, 3 barriers/step.
// ---------------------------------------------------------------------------

typedef _Float16 h2 __attribute__((ext_vector_type(2)));

static __device__ __forceinline__ float fdot2(unsigned a, unsigned b, float c) {
#if __has_builtin(__builtin_amdgcn_fdot2)
  return __builtin_amdgcn_fdot2(__builtin_bit_cast(h2, a),
                                __builtin_bit_cast(h2, b), c, false);
#else
  h2 x = __builtin_bit_cast(h2, a), y = __builtin_bit_cast(h2, b);
  return c + (float)x[0] * (float)y[0] + (float)x[1] * (float)y[1];
#endif
}

static __device__ __forceinline__ unsigned short f16b(float v) {
  _Float16 h = (_Float16)v;
  return __builtin_bit_cast(unsigned short, h);
}

static __device__ __forceinline__ float sigm(float x) {
  return 1.0f / (1.0f + __expf(-x));
}
static __device__ __forceinline__ float tanh_(float x) {
  return 1.0f - 2.0f / (1.0f + __expf(2.0f * x));
}

// rwp[l][d][o] = pack(f16(rec_w[l][o][2d]), f16(rec_w[l][o][2d+1]))
__global__ __launch_bounds__(256) void prep_rw(const float* __restrict__ rw,
                                               unsigned* __restrict__ rwp) {
  int idx = blockIdx.x * 256 + threadIdx.x;
  if (idx >= 3 * 128 * 1024) return;
  int o = idx & 1023, d = (idx >> 10) & 127, l = idx >> 17;
  const float* src = rw + (l * 1024 + o) * 256 + 2 * d;
  unsigned v = (unsigned)f16b(src[0]) | ((unsigned)f16b(src[1]) << 16);
  rwp[idx] = v;
}

// cwp[jj][o][k][d] = pack(f16(conv_w[jj][o][2d][k]), f16(conv_w[jj][o][2d+1][k]))
__global__ __launch_bounds__(256) void prep_cw(const float* __restrict__ cw,
                                               unsigned* __restrict__ cwp) {
  int idx = blockIdx.x * 256 + threadIdx.x;
  if (idx >= 6 * 1024 * 2 * 128) return;
  int d = idx & 127, k = (idx >> 7) & 1, o = (idx >> 8) & 1023, jj = idx >> 18;
  const float* src = cw + ((jj * 1024 + o) * 256 + 2 * d) * 2 + k;
  unsigned v = (unsigned)f16b(src[0]) | ((unsigned)f16b(src[2]) << 16);
  cwp[idx] = v;
}

// x0[b,w,h] = sum_c emb_w[h,c]*input[b,c,w] + emb_b[h]; store f16 + out tail.
__global__ __launch_bounds__(256) void emb_kernel(
    const float* __restrict__ inp, const float* __restrict__ ew,
    const float* __restrict__ eb, unsigned short* __restrict__ x0f,
    float* __restrict__ out) {
  __shared__ float xt[32][65];
  __shared__ float wt[64][33];
  int b = blockIdx.z, w0 = blockIdx.x * 64, h0 = blockIdx.y * 64;
  int tid = threadIdx.x, tx = tid & 15, ty = tid >> 4;
  float acc[4][4] = {};
  for (int c0 = 0; c0 < 128; c0 += 32) {
    __syncthreads();
#pragma unroll
    for (int i = 0; i < 8; i++) {
      int f = i * 256 + tid, c = f >> 6, wl = f & 63;
      xt[c][wl] = inp[(b * 128 + c0 + c) * 512 + w0 + wl];
    }
#pragma unroll
    for (int i = 0; i < 8; i++) {
      int f = i * 256 + tid, h = f >> 5, c = f & 31;
      wt[h][c] = ew[(h0 + h) * 128 + c0 + c];
    }
    __syncthreads();
#pragma unroll
    for (int c = 0; c < 32; c++) {
      float xv[4], wv[4];
#pragma unroll
      for (int q = 0; q < 4; q++) xv[q] = xt[c][ty * 4 + q];
#pragma unroll
      for (int p = 0; p < 4; p++) wv[p] = wt[tx * 4 + p][c];
#pragma unroll
      for (int q = 0; q < 4; q++)
#pragma unroll
        for (int p = 0; p < 4; p++) acc[q][p] += xv[q] * wv[p];
    }
  }
#pragma unroll
  for (int q = 0; q < 4; q++) {
    int w = w0 + ty * 4 + q;
#pragma unroll
    for (int p = 0; p < 4; p++) {
      int h = h0 + tx * 4 + p;
      float v = acc[q][p] + eb[h];
      x0f[(b * 512 + w) * 256 + h] = f16b(v);
      if (w >= 510) out[(b * 256 + h) * 2 + (w - 510)] = v;  // x[0] tail
    }
  }
}

// ig[b,w,o] = sum_j sum_{i,k} xpad_j[b,w-1+k,i] * cw[off+j][o,i,k] + biases
__global__ __launch_bounds__(256) void conv_kernel(
    const unsigned short* __restrict__ xf, const unsigned* __restrict__ cwp,
    const float* __restrict__ cb, const float* __restrict__ hidden,
    unsigned short* __restrict__ igf, int l, int off) {
  __shared__ __align__(16) unsigned xs[65][20];    // [pad-col][dw16], stride 20
  __shared__ __align__(16) unsigned wsm[2][16][66];// [k][dw16][o], pad 66
  int b = blockIdx.z, w0 = blockIdx.x * 64, o0 = blockIdx.y * 64;
  int tid = threadIdx.x, tx = tid & 15, ty = tid >> 4;
  float acc[4][4] = {};
  int nl = l + 1;
  for (int j = 0; j < nl; j++) {
    const unsigned* xj = (const unsigned*)(xf + j * 4194304 + b * 512 * 256);
    const unsigned* cwj = cwp + (off + j) * 262144;
    for (int c0 = 0; c0 < 256; c0 += 32) {
      int d0 = c0 >> 1;
      __syncthreads();
#pragma unroll
      for (int i = 0; i < 5; i++) {
        int f = i * 256 + tid;
        if (f < 1040) {
          int col = f >> 4, dw = f & 15;
          int w = w0 - 1 + col;
          unsigned v;
          if (w >= 0) {
            v = xj[w * 128 + d0 + dw];
          } else {  // left pad: hidden[j][b][i][1]
            const float* hp = hidden + ((j * 32 + b) * 256 + 2 * (d0 + dw)) * 2 + 1;
            v = (unsigned)f16b(hp[0]) | ((unsigned)f16b(hp[2]) << 16);
          }
          xs[col][dw] = v;
        }
      }
#pragma unroll
      for (int i = 0; i < 8; i++) {
        int f = i * 256 + tid;
        int oo = f >> 5, k = (f >> 4) & 1, dw = f & 15;
        wsm[k][dw][oo] = cwj[(o0 + oo) * 256 + k * 128 + d0 + dw];
      }
      __syncthreads();
#pragma unroll
      for (int g = 0; g < 4; g++) {
        uint4 xv[5];
#pragma unroll
        for (int q = 0; q < 5; q++)
          xv[q] = *(const uint4*)&xs[ty * 4 + q][g * 4];
#pragma unroll
        for (int p = 0; p < 4; p++) {
          unsigned wv0[4], wv1[4];
#pragma unroll
          for (int r = 0; r < 4; r++) {
            wv0[r] = wsm[0][g * 4 + r][tx * 4 + p];
            wv1[r] = wsm[1][g * 4 + r][tx * 4 + p];
          }
#pragma unroll
          for (int q = 0; q < 4; q++) {
            float a = acc[q][p];
            a = fdot2(wv0[0], xv[q].x, a);
            a = fdot2(wv0[1], xv[q].y, a);
            a = fdot2(wv0[2], xv[q].z, a);
            a = fdot2(wv0[3], xv[q].w, a);
            a = fdot2(wv1[0], xv[q + 1].x, a);
            a = fdot2(wv1[1], xv[q + 1].y, a);
            a = fdot2(wv1[2], xv[q + 1].z, a);
            a = fdot2(wv1[3], xv[q + 1].w, a);
            acc[q][p] = a;
          }
        }
      }
    }
  }
#pragma unroll
  for (int p = 0; p < 4; p++) {
    int o = o0 + tx * 4 + p;
    float bias = 0.f;
    for (int j = 0; j < nl; j++) bias += cb[(off + j) * 1024 + o];
#pragma unroll
    for (int q = 0; q < 4; q++) {
      int w = w0 + ty * 4 + q;
      igf[(b * 512 + w) * 1024 + o] = f16b(acc[q][p] + bias);
    }
  }
}

// One WG per batch; thread o owns gate row o. 512 sequential steps.
__global__ __launch_bounds__(1024) void rec_kernel(
    const _Float16* __restrict__ igf, const unsigned* __restrict__ rwp_l,
    const float* __restrict__ rb, const float* __restrict__ aw,
    const float* __restrict__ hidden, const float* __restrict__ context,
    int l, unsigned short* __restrict__ xnext, float* __restrict__ out) {
  __shared__ __align__(16) unsigned rw_lds[1024 * 15];  // 61,440 B
  __shared__ __align__(16) unsigned short hx_half[256]; // hx as f16
  __shared__ __align__(16) _Float16 gates[1024];
  __shared__ float red[4];
  int b = blockIdx.x, o = threadIdx.x;

  unsigned rwreg[104];
#pragma unroll
  for (int d = 0; d < 104; d++) rwreg[d] = rwp_l[(d << 10) + o];
#pragma unroll
  for (int i = 0; i < 15; i++) rw_lds[o * 15 + i] = rwp_l[((104 + i) << 10) + o];

  float rbv = rb[o];
  float cx = 0.f, awj = 0.f;
  if (o < 256) {
    awj = aw[o];
    float h0 = hidden[(((l + 1) * 32 + b) * 256 + o) * 2 + 1];
    cx = context[((l * 32 + b) * 256 + o) * 2 + 1];
    hx_half[o] = f16b(h0);
  }
  __syncthreads();

  const _Float16* igp = igf + (b * 512) * 1024 + o;
  const unsigned* rl = &rw_lds[o * 15];

  for (int t = 0; t < 512; t++) {
    float gin = (float)igp[t * 1024];
    unsigned gt[9];
#pragma unroll
    for (int i = 0; i < 9; i++) gt[i] = rwp_l[((119 + i) << 10) + o];

    float acc0 = gin + rbv, acc1 = 0.f;
    const uint4* hq4 = (const uint4*)hx_half;
#pragma unroll
    for (int q = 0; q < 26; q++) {
      uint4 h = hq4[q];
      float* a = (q & 1) ? &acc1 : &acc0;
      *a = fdot2(rwreg[4 * q + 0], h.x, *a);
      *a = fdot2(rwreg[4 * q + 1], h.y, *a);
      *a = fdot2(rwreg[4 * q + 2], h.z, *a);
      *a = fdot2(rwreg[4 * q + 3], h.w, *a);
    }
    {
      uint4 h = hq4[26];
      acc0 = fdot2(rl[0], h.x, acc0);
      acc0 = fdot2(rl[1], h.y, acc0);
      acc0 = fdot2(rl[2], h.z, acc0);
      acc0 = fdot2(rl[3], h.w, acc0);
      h = hq4[27];
      acc1 = fdot2(rl[4], h.x, acc1);
      acc1 = fdot2(rl[5], h.y, acc1);
      acc1 = fdot2(rl[6], h.z, acc1);
      acc1 = fdot2(rl[7], h.w, acc1);
      h = hq4[28];
      acc0 = fdot2(rl[8], h.x, acc0);
      acc0 = fdot2(rl[9], h.y, acc0);
      acc0 = fdot2(rl[10], h.z, acc0);
      acc0 = fdot2(rl[11], h.w, acc0);
      h = hq4[29];
      acc1 = fdot2(rl[12], h.x, acc1);
      acc1 = fdot2(rl[13], h.y, acc1);
      acc1 = fdot2(rl[14], h.z, acc1);
      acc1 = fdot2(gt[0], h.w, acc1);
      h = hq4[30];
      acc0 = fdot2(gt[1], h.x, acc0);
      acc0 = fdot2(gt[2], h.y, acc0);
      acc0 = fdot2(gt[3], h.z, acc0);
      acc0 = fdot2(gt[4], h.w, acc0);
      h = hq4[31];
      acc1 = fdot2(gt[5], h.x, acc1);
      acc1 = fdot2(gt[6], h.y, acc1);
      acc1 = fdot2(gt[7], h.z, acc1);
      acc1 = fdot2(gt[8], h.w, acc1);
    }
    gates[o] = (_Float16)(acc0 + acc1);
    __syncthreads();

    float h_val = 0.f;
    if (o < 256) {
      float g_i = (float)gates[o];
      float g_f = (float)gates[256 + o];
      float g_c = (float)gates[512 + o];
      float g_o = (float)gates[768 + o];
      float si = sigm(g_i), sf = sigm(g_f), tc = tanh_(g_c), so = sigm(g_o);
      cx = sf * cx + si * tc;
      h_val = so * tanh_(cx);
      float part = h_val * awj;
#pragma unroll
      for (int s = 32; s > 0; s >>= 1) part += __shfl_xor(part, s);
      if ((o & 63) == 0) red[o >> 6] = part;
    }
    __syncthreads();
    if (o < 256) {
      float a_ = sigm(red[0] + red[1] + red[2] + red[3]);
      float hg = (t < 511) ? h_val * a_ : h_val;
      hx_half[o] = f16b(hg);
      xnext[(b * 512 + t) * 256 + o] = f16b(hg);
      if (t >= 510) {
        out[(((l + 1) * 32 + b) * 256 + o) * 2 + (t - 510)] = hg;          // x tail
        out[65536 + ((l * 32 + b) * 256 + o) * 2 + (t - 510)] = cx;        // nc tail
      }
      if (o == 0 && t < 511) out[114688 + (l * 32 + b) * 511 + t] = a_;    // attn
    }
    __syncthreads();
  }
}

extern "C" void kernel_launch(void* const* d_in, const int* in_sizes, int n_in,
                              void* d_out, int out_size, void* d_ws,
                              size_t ws_size, hipStream_t stream) {
  const float* input  = (const float*)d_in[0];
  const float* hidden = (const float*)d_in[1];
  const float* context= (const float*)d_in[2];
  const float* emb_w  = (const float*)d_in[3];
  const float* emb_b  = (const float*)d_in[4];
  const float* conv_w = (const float*)d_in[5];
  const float* conv_b = (const float*)d_in[6];
  const float* rec_w  = (const float*)d_in[7];
  const float* rec_b  = (const float*)d_in[8];
  const float* attn_w = (const float*)d_in[9];
  float* out = (float*)d_out;

  char* ws = (char*)d_ws;
  unsigned short* xf16 = (unsigned short*)ws;                    // 4 x 4,194,304 f16 = 32 MB
  _Float16* igf = (_Float16*)(ws + 33554432);                    // 16,777,216 f16 = 32 MB
  unsigned* rwp = (unsigned*)(ws + 67108864);                    // 1.5 MB
  unsigned* cwp = (unsigned*)(ws + 68681728);                    // 6 MB

  hipLaunchKernelGGL(prep_rw, dim3(1536), dim3(256), 0, stream, rec_w, rwp);
  hipLaunchKernelGGL(prep_cw, dim3(6144), dim3(256), 0, stream, conv_w, cwp);
  hipLaunchKernelGGL(emb_kernel, dim3(8, 4, 32), dim3(256), 0, stream,
                     input, emb_w, emb_b, xf16, out);
  int off = 0;
  for (int l = 0; l < 3; l++) {
    hipLaunchKernelGGL(conv_kernel, dim3(8, 16, 32), dim3(256), 0, stream,
                       xf16, cwp, conv_b, hidden, (unsigned short*)igf, l, off);
    hipLaunchKernelGGL(rec_kernel, dim3(32), dim3(1024), 0, stream,
                       igf, rwp + l * 131072, rec_b + l * 1024,
                       attn_w + l * 256, hidden, context, l,
                       xf16 + (l + 1) * 4194304, out);
    off += l + 1;
  }
}